// Round 9
// baseline (64.158 us; speedup 1.0000x reference)
//
#include <hip/hip_runtime.h>

#define NN 2048
#define BB 4
#define IN_F 128
#define OUT_F 64

typedef __attribute__((ext_vector_type(8))) short short8;
typedef __attribute__((ext_vector_type(4))) float f32x4;
typedef __attribute__((ext_vector_type(4))) int i32x4;

__device__ __forceinline__ ushort f2bf(float f) {
  uint u = __float_as_uint(f);
  uint r = (u + 0x7fffu + ((u >> 16) & 1u)) >> 16;   // RNE, finite values
  return (ushort)r;
}
__device__ __forceinline__ float bf2f(ushort s) {
  return __uint_as_float(((uint)s) << 16);
}

// Kernel 1: per row: wh[o] = h[row].W[:,o] (f32) -> Whbf bf16 row-major;
// el/er via wave reduce.
__global__ __launch_bounds__(64) void wh_el_er_kernel(
    const float* __restrict__ h, const float* __restrict__ W,
    const float* __restrict__ a, ushort* __restrict__ Whbf,
    float* __restrict__ el, float* __restrict__ er) {
  int row = blockIdx.x;           // b*NN + n
  int o = threadIdx.x;
  const float* hr = h + (size_t)row * IN_F;
  float wh = 0.f;
  #pragma unroll 8
  for (int f = 0; f < IN_F; ++f) wh += hr[f] * W[f * OUT_F + o];
  Whbf[(size_t)row * OUT_F + o] = f2bf(wh);
  float vl = wh * a[o];
  float vr = wh * a[OUT_F + o];
  #pragma unroll
  for (int d = 32; d > 0; d >>= 1) {
    vl += __shfl_down(vl, d);
    vr += __shfl_down(vr, d);
  }
  if (o == 0) { el[row] = vl; er[row] = vr; }
}

// Kernel 1b: WhbfT[b][o][j] = Whbf[b][j][o] (bf16 transpose, 64x2048/batch).
__global__ __launch_bounds__(256) void transpose_kernel(
    const ushort* __restrict__ Whbf, ushort* __restrict__ WhbfT) {
  __shared__ uint tile[64][65];
  int b = blockIdx.x >> 5;
  int j0 = (blockIdx.x & 31) << 6;
  int t = threadIdx.x;
  int o = t & 63, jg = t >> 6;
  #pragma unroll
  for (int m = 0; m < 16; ++m) {
    int jj = jg * 16 + m;
    tile[jj][o] = (uint)Whbf[((size_t)(b * NN + j0 + jj)) * OUT_F + o];
  }
  __syncthreads();
  int oo = t >> 2, grp = t & 3;
  uint out[8];
  #pragma unroll
  for (int m = 0; m < 16; m += 2) {
    uint u0 = tile[grp * 16 + m][oo];
    uint u1 = tile[grp * 16 + m + 1][oo];
    out[m >> 1] = u0 | (u1 << 16);
  }
  uint4* dst = (uint4*)(WhbfT + ((size_t)(b * OUT_F + oo)) * NN + j0 + grp * 16);
  dst[0] = *(uint4*)&out[0];
  dst[1] = *(uint4*)&out[4];
}

// Kernel 2: persistent block = TWO sequential 8-row tiles (software pipeline:
// tile t's attention-store drain overlaps tile t+1's adj loads + MFMA).
// 512 threads (8 waves), 1 row/wave in phase 1. LDS ~45 KB.
// Per tile: coalesced no-max streaming exp -> pbuf (bf16, XOR-swizzled) ->
// barrier -> attention stores (fire-and-forget) -> MFMA p @ Wh
// (wave = o-tile x k-half, A rows 8..15 zeroed) -> reduce -> epilogue.
__global__ __launch_bounds__(512, 4) void attn_kernel(
    const int* __restrict__ adj, const ushort* __restrict__ WhbfT,
    const float* __restrict__ el, const float* __restrict__ er,
    float* __restrict__ attn_out, float* __restrict__ hprime) {
  __shared__ __align__(16) char pbuf[8 * 4096];   // 32 KB: p bf16 [8][2048]
  __shared__ float ers[NN];                       // 8 KB
  __shared__ float red[4][8][17];                 // 2.2 KB cross-khalf reduce
  __shared__ float sinv[8];

  int blk = blockIdx.x;
  int b = blk >> 7;             // 128 blocks per batch
  int q = blk & 127;            // each handles rows [q*16, q*16+16) as 2 tiles
  int tid = threadIdx.x;
  int w = tid >> 6, lane = tid & 63;

  // stage er for this batch into LDS (reused across both tiles)
  ((f32x4*)ers)[tid] = ((const f32x4*)(er + (size_t)b * NN))[tid];
  __syncthreads();

  for (int t = 0; t < 2; ++t) {
    int i0 = q * 16 + t * 8;
    int i = i0 + w;

    // ---- Phase 1: streaming masked exp, 1 row per wave, coalesced ----
    float eli = el[(size_t)b * NN + i];
    const i32x4* arow4 = (const i32x4*)(adj + ((size_t)(b * NN + i)) * NN);

    uint2 pva[8];
    float ssum = 0.f;
    #pragma unroll
    for (int it = 0; it < 8; ++it) {
      i32x4 av = arow4[lane + 64 * it];
      f32x4 ev = *(const f32x4*)&ers[(lane + 64 * it) * 4];
      float evv[4] = {ev.x, ev.y, ev.z, ev.w};
      int   avv[4] = {av.x, av.y, av.z, av.w};
      float pe[4];
      #pragma unroll
      for (int k = 0; k < 4; ++k) {
        float e = eli + evv[k];
        e = e > 0.f ? e : 0.2f * e;          // leaky_relu 0.2
        float x = __expf(e);                 // |e| <~ 12, f32-safe unnormalized
        pe[k] = avv[k] > 0 ? x : 0.f;        // masked -> 0
        ssum += pe[k];
      }
      uint2 w2;
      w2.x = (uint)f2bf(pe[0]) | ((uint)f2bf(pe[1]) << 16);
      w2.y = (uint)f2bf(pe[2]) | ((uint)f2bf(pe[3]) << 16);
      pva[it] = w2;
    }
    #pragma unroll
    for (int d = 32; d > 0; d >>= 1) ssum += __shfl_xor(ssum, d);
    float inv = 1.f / ssum;
    if (lane == 0) sinv[w] = inv;

    {
      char* prow = pbuf + w * 4096;
      int sw = w << 4;
      #pragma unroll
      for (int it = 0; it < 8; ++it)
        *(uint2*)(prow + (((lane + 64 * it) * 8) ^ sw)) = pva[it];
    }
    __syncthreads();

    // ---- attention stores: issue now, drain overlaps MFMA + next tile ----
    {
      f32x4* orow = (f32x4*)(attn_out + ((size_t)(b * NN + i)) * NN);
      #pragma unroll
      for (int it = 0; it < 8; ++it) {
        uint2 w2 = pva[it];
        f32x4 v;
        v.x = bf2f((ushort)(w2.x & 0xffff)) * inv;
        v.y = bf2f((ushort)(w2.x >> 16)) * inv;
        v.z = bf2f((ushort)(w2.y & 0xffff)) * inv;
        v.w = bf2f((ushort)(w2.y >> 16)) * inv;
        orow[lane + 64 * it] = v;
      }
    }

    // ---- Phase 2: MFMA p @ Wh; wave = (o-tile, k-half) ----
    int ntile = w >> 1, khalf = w & 1;
    int o0 = ntile * 16;
    int lo16 = lane & 15, hi4 = lane >> 4;

    const char* prowA = pbuf + (lo16 & 7) * 4096;
    int swA = (lo16 & 7) << 4;
    const ushort* brow = WhbfT + ((size_t)(b * OUT_F + o0 + lo16)) * NN;
    short8 zero8 = {0, 0, 0, 0, 0, 0, 0, 0};

    f32x4 acc = {0.f, 0.f, 0.f, 0.f};
    #pragma unroll 4
    for (int kk = 0; kk < 32; ++kk) {
      int kbase = khalf * 1024 + kk * 32 + hi4 * 8;
      short8 afrag = *(const short8*)(prowA + ((kbase * 2) ^ swA));
      afrag = lo16 < 8 ? afrag : zero8;      // A rows 8..15 are zero
      short8 bfrag = *(const short8*)(brow + kbase);
      acc = __builtin_amdgcn_mfma_f32_16x16x32_bf16(afrag, bfrag, acc, 0, 0, 0);
    }

    if (khalf == 1) {
      #pragma unroll
      for (int qq = 0; qq < 4; ++qq) {
        int crow = hi4 * 4 + qq;
        if (crow < 8) red[ntile][crow][lo16] = acc[qq];
      }
    }
    __syncthreads();
    if (khalf == 0 && hi4 < 2) {
      #pragma unroll
      for (int qq = 0; qq < 4; ++qq) {
        int crow = hi4 * 4 + qq;
        float v = (acc[qq] + red[ntile][crow][lo16]) * sinv[crow];
        v = v > 0.f ? v : 0.01f * v;         // leaky_relu 0.01
        hprime[((size_t)(b * NN + i0 + crow)) * OUT_F + o0 + lo16] = v;
      }
    }
    __syncthreads();   // pbuf/red/sinv safe for next tile
  }
}

extern "C" void kernel_launch(void* const* d_in, const int* in_sizes, int n_in,
                              void* d_out, int out_size, void* d_ws, size_t ws_size,
                              hipStream_t stream) {
  const float* h  = (const float*)d_in[0];
  const int* adj  = (const int*)d_in[1];
  const float* W  = (const float*)d_in[2];
  const float* a  = (const float*)d_in[3];

  float* hprime   = (float*)d_out;                           // B*N*OUT_F
  float* attn_out = (float*)d_out + (size_t)BB * NN * OUT_F; // B*N*N

  // workspace: Whbf bf16 [B*N*64], WhbfT bf16 [B*64*N], el f32, er f32
  ushort* Whbf  = (ushort*)d_ws;
  ushort* WhbfT = Whbf + (size_t)BB * NN * OUT_F;
  float* el = (float*)(WhbfT + (size_t)BB * OUT_F * NN);
  float* er = el + (size_t)BB * NN;

  hipLaunchKernelGGL(wh_el_er_kernel, dim3(BB * NN), dim3(64), 0, stream,
                     h, W, a, Whbf, el, er);
  hipLaunchKernelGGL(transpose_kernel, dim3(BB * (NN / 64)), dim3(256), 0, stream,
                     Whbf, WhbfT);
  hipLaunchKernelGGL(attn_kernel, dim3(BB * (NN / 16)), dim3(512), 0, stream,
                     adj, WhbfT, el, er, attn_out, hprime);
}

// Round 10
// 63.031 us; speedup vs baseline: 1.0179x; 1.0179x over previous
//
#include <hip/hip_runtime.h>

#define NN 2048
#define BB 4
#define IN_F 128
#define OUT_F 64

typedef __attribute__((ext_vector_type(8))) short short8;
typedef __attribute__((ext_vector_type(4))) float f32x4;
typedef __attribute__((ext_vector_type(4))) int i32x4;

__device__ __forceinline__ ushort f2bf(float f) {
  uint u = __float_as_uint(f);
  uint r = (u + 0x7fffu + ((u >> 16) & 1u)) >> 16;   // RNE, finite values
  return (ushort)r;
}
__device__ __forceinline__ float bf2f(ushort s) {
  return __uint_as_float(((uint)s) << 16);
}

// Kernel 1: per row: wh[o] = h[row].W[:,o] (f32) -> Whbf bf16 row-major;
// el/er via wave reduce.
__global__ __launch_bounds__(64) void wh_el_er_kernel(
    const float* __restrict__ h, const float* __restrict__ W,
    const float* __restrict__ a, ushort* __restrict__ Whbf,
    float* __restrict__ el, float* __restrict__ er) {
  int row = blockIdx.x;           // b*NN + n
  int o = threadIdx.x;
  const float* hr = h + (size_t)row * IN_F;
  float wh = 0.f;
  #pragma unroll 8
  for (int f = 0; f < IN_F; ++f) wh += hr[f] * W[f * OUT_F + o];
  Whbf[(size_t)row * OUT_F + o] = f2bf(wh);
  float vl = wh * a[o];
  float vr = wh * a[OUT_F + o];
  #pragma unroll
  for (int d = 32; d > 0; d >>= 1) {
    vl += __shfl_down(vl, d);
    vr += __shfl_down(vr, d);
  }
  if (o == 0) { el[row] = vl; er[row] = vr; }
}

// Kernel 1b: WhbfT[b][o][j] = Whbf[b][j][o] (bf16 transpose, 64x2048/batch).
__global__ __launch_bounds__(256) void transpose_kernel(
    const ushort* __restrict__ Whbf, ushort* __restrict__ WhbfT) {
  __shared__ uint tile[64][65];
  int b = blockIdx.x >> 5;
  int j0 = (blockIdx.x & 31) << 6;
  int t = threadIdx.x;
  int o = t & 63, jg = t >> 6;
  #pragma unroll
  for (int m = 0; m < 16; ++m) {
    int jj = jg * 16 + m;
    tile[jj][o] = (uint)Whbf[((size_t)(b * NN + j0 + jj)) * OUT_F + o];
  }
  __syncthreads();
  int oo = t >> 2, grp = t & 3;
  uint out[8];
  #pragma unroll
  for (int m = 0; m < 16; m += 2) {
    uint u0 = tile[grp * 16 + m][oo];
    uint u1 = tile[grp * 16 + m + 1][oo];
    out[m >> 1] = u0 | (u1 << 16);
  }
  uint4* dst = (uint4*)(WhbfT + ((size_t)(b * OUT_F + oo)) * NN + j0 + grp * 16);
  dst[0] = *(uint4*)&out[0];
  dst[1] = *(uint4*)&out[4];
}

// Kernel A: pure-streaming masked softmax. 1 row per wave, 4 waves/block,
// no LDS, no barriers. Writes UNNORMALIZED bf16 p into the FIRST HALF of the
// row's attention slot (in-place staging; kernel B expands to f32) + 1/sum.
__global__ __launch_bounds__(256) void softmax_kernel(
    const int* __restrict__ adj, const float* __restrict__ el,
    const float* __restrict__ er, float* __restrict__ attn_out,
    float* __restrict__ sinv) {
  int lane = threadIdx.x & 63;
  int row = blockIdx.x * 4 + (threadIdx.x >> 6);   // b*NN + i
  int b = row >> 11;
  float eli = el[row];
  const i32x4* arow4 = (const i32x4*)(adj + (size_t)row * NN);
  const f32x4* er4 = (const f32x4*)(er + ((size_t)b << 11));

  uint2 pva[8];
  float ssum = 0.f;
  #pragma unroll
  for (int it = 0; it < 8; ++it) {
    i32x4 av = arow4[lane + 64 * it];
    f32x4 ev = er4[lane + 64 * it];
    float evv[4] = {ev.x, ev.y, ev.z, ev.w};
    int   avv[4] = {av.x, av.y, av.z, av.w};
    float pe[4];
    #pragma unroll
    for (int k = 0; k < 4; ++k) {
      float e = eli + evv[k];
      e = fmaxf(e, 0.2f * e);              // leaky_relu 0.2
      float x = __expf(e);                 // |e| <~ 12, f32-safe unnormalized
      pe[k] = avv[k] > 0 ? x : 0.f;        // masked -> 0
      ssum += pe[k];
    }
    uint2 w2;
    w2.x = (uint)f2bf(pe[0]) | ((uint)f2bf(pe[1]) << 16);
    w2.y = (uint)f2bf(pe[2]) | ((uint)f2bf(pe[3]) << 16);
    pva[it] = w2;
  }
  #pragma unroll
  for (int d = 32; d > 0; d >>= 1) ssum += __shfl_xor(ssum, d);

  ushort* prow = (ushort*)(attn_out + (size_t)row * NN);
  #pragma unroll
  for (int it = 0; it < 8; ++it)
    *(uint2*)(prow + (lane + 64 * it) * 4) = pva[it];
  if (lane == 0) sinv[row] = 1.f / ssum;
}

// Kernel B: block = 16 rows, 512 threads (8 waves), 2 rows/wave.
// Phase 1: load bf16 p rows (L3-hot) -> swizzled LDS pbuf; barrier (compiler
// drains vmcnt -> in-place overwrite below is safe).
// Then: pure coalesced f32 attention stores (normalized) whose drain overlaps
// the MFMA phase; Phase 2: h_prime = lrelu(inv * (p @ Wh), 0.01) via
// mfma_f32_16x16x32_bf16 (wave = o-tile x k-half), cross-khalf LDS reduce.
__global__ __launch_bounds__(512, 4) void pv_kernel(
    const ushort* __restrict__ WhbfT, const float* __restrict__ sinv,
    float* __restrict__ attn_out, float* __restrict__ hprime) {
  __shared__ __align__(16) char pbuf[16 * 4096];  // 64 KB: p bf16 [16][2048]
  __shared__ float red[4][16][17];                // 4.4 KB cross-khalf reduce

  int blk = blockIdx.x;
  int b = blk >> 7;             // 128 blocks per batch
  int i0 = (blk & 127) << 4;
  int tid = threadIdx.x;
  int wave = tid >> 6, lane = tid & 63;

  int r0 = wave * 2, r1 = r0 + 1;
  int ga = b * NN + i0 + r0, gb = b * NN + i0 + r1;   // global row ids

  // ---- Phase 1: read bf16 p rows, stage to swizzled LDS ----
  const ushort* pr0 = (const ushort*)(attn_out + (size_t)ga * NN);
  const ushort* pr1 = (const ushort*)(attn_out + (size_t)gb * NN);
  uint2 pva0[8], pva1[8];
  #pragma unroll
  for (int it = 0; it < 8; ++it) {
    pva0[it] = *(const uint2*)(pr0 + (lane + 64 * it) * 4);
    pva1[it] = *(const uint2*)(pr1 + (lane + 64 * it) * 4);
  }
  {
    char* lr0 = pbuf + r0 * 4096;
    char* lr1 = pbuf + r1 * 4096;
    int sw0 = (r0 & 7) << 4, sw1 = (r1 & 7) << 4;
    #pragma unroll
    for (int it = 0; it < 8; ++it) {
      *(uint2*)(lr0 + (((lane + 64 * it) * 8) ^ sw0)) = pva0[it];
      *(uint2*)(lr1 + (((lane + 64 * it) * 8) ^ sw1)) = pva1[it];
    }
  }
  __syncthreads();   // all loads drained -> safe to overwrite rows in place

  // ---- attention stores (pure coalesced f32); drain overlaps MFMA ----
  {
    float inv0 = sinv[ga], inv1 = sinv[gb];
    f32x4* or0 = (f32x4*)(attn_out + (size_t)ga * NN);
    f32x4* or1 = (f32x4*)(attn_out + (size_t)gb * NN);
    #pragma unroll
    for (int it = 0; it < 8; ++it) {
      uint2 w0 = pva0[it], w1 = pva1[it];
      f32x4 v0, v1;
      v0.x = bf2f((ushort)(w0.x & 0xffff)) * inv0;
      v0.y = bf2f((ushort)(w0.x >> 16)) * inv0;
      v0.z = bf2f((ushort)(w0.y & 0xffff)) * inv0;
      v0.w = bf2f((ushort)(w0.y >> 16)) * inv0;
      or0[lane + 64 * it] = v0;
      v1.x = bf2f((ushort)(w1.x & 0xffff)) * inv1;
      v1.y = bf2f((ushort)(w1.x >> 16)) * inv1;
      v1.z = bf2f((ushort)(w1.y & 0xffff)) * inv1;
      v1.w = bf2f((ushort)(w1.y >> 16)) * inv1;
      or1[lane + 64 * it] = v1;
    }
  }

  // ---- Phase 2: MFMA p @ Wh; wave = (ntile = w>>1, khalf = w&1) ----
  int ntile = wave >> 1, khalf = wave & 1;
  int o0 = ntile * 16;
  int lo16 = lane & 15, hi4 = lane >> 4;

  const char* prowA = pbuf + lo16 * 4096;
  int swA = (lo16 & 7) << 4;
  const ushort* brow = WhbfT + ((size_t)(b * OUT_F + o0 + lo16)) * NN;

  f32x4 acc = {0.f, 0.f, 0.f, 0.f};
  #pragma unroll 4
  for (int kk = 0; kk < 32; ++kk) {
    int kbase = khalf * 1024 + kk * 32 + hi4 * 8;
    short8 afrag = *(const short8*)(prowA + ((kbase * 2) ^ swA));
    short8 bfrag = *(const short8*)(brow + kbase);
    acc = __builtin_amdgcn_mfma_f32_16x16x32_bf16(afrag, bfrag, acc, 0, 0, 0);
  }

  // ---- cross-khalf reduce + epilogue ----
  if (khalf == 1) {
    #pragma unroll
    for (int q = 0; q < 4; ++q) red[ntile][hi4 * 4 + q][lo16] = acc[q];
  }
  __syncthreads();
  if (khalf == 0) {
    #pragma unroll
    for (int q = 0; q < 4; ++q) {
      int crow = hi4 * 4 + q;
      float v = (acc[q] + red[ntile][crow][lo16]) * sinv[b * NN + i0 + crow];
      v = v > 0.f ? v : 0.01f * v;           // leaky_relu 0.01
      hprime[((size_t)(b * NN + i0 + crow)) * OUT_F + o0 + lo16] = v;
    }
  }
}

extern "C" void kernel_launch(void* const* d_in, const int* in_sizes, int n_in,
                              void* d_out, int out_size, void* d_ws, size_t ws_size,
                              hipStream_t stream) {
  const float* h  = (const float*)d_in[0];
  const int* adj  = (const int*)d_in[1];
  const float* W  = (const float*)d_in[2];
  const float* a  = (const float*)d_in[3];

  float* hprime   = (float*)d_out;                           // B*N*OUT_F
  float* attn_out = (float*)d_out + (size_t)BB * NN * OUT_F; // B*N*N

  // workspace: Whbf bf16 [B*N*64], WhbfT bf16 [B*64*N], el, er, sinv (~2.1 MB)
  ushort* Whbf  = (ushort*)d_ws;
  ushort* WhbfT = Whbf + (size_t)BB * NN * OUT_F;
  float* el = (float*)(WhbfT + (size_t)BB * OUT_F * NN);
  float* er = el + (size_t)BB * NN;
  float* sinv = er + (size_t)BB * NN;

  hipLaunchKernelGGL(wh_el_er_kernel, dim3(BB * NN), dim3(64), 0, stream,
                     h, W, a, Whbf, el, er);
  hipLaunchKernelGGL(transpose_kernel, dim3(BB * (NN / 64)), dim3(256), 0, stream,
                     Whbf, WhbfT);
  hipLaunchKernelGGL(softmax_kernel, dim3(BB * NN / 4), dim3(256), 0, stream,
                     adj, el, er, attn_out, sinv);
  hipLaunchKernelGGL(pv_kernel, dim3(BB * (NN / 16)), dim3(512), 0, stream,
                     WhbfT, sinv, attn_out, hprime);
}

// Round 11
// 58.048 us; speedup vs baseline: 1.1053x; 1.0858x over previous
//
#include <hip/hip_runtime.h>

#define NN 2048
#define BB 4
#define IN_F 128
#define OUT_F 64

typedef __attribute__((ext_vector_type(8))) short short8;
typedef __attribute__((ext_vector_type(4))) float f32x4;
typedef __attribute__((ext_vector_type(4))) int i32x4;

__device__ __forceinline__ ushort f2bf(float f) {
  uint u = __float_as_uint(f);
  uint r = (u + 0x7fffu + ((u >> 16) & 1u)) >> 16;   // RNE, finite values
  return (ushort)r;
}
__device__ __forceinline__ float bf2f(ushort s) {
  return __uint_as_float(((uint)s) << 16);
}

// Kernel 1: per row: wh[o] = h[row].W[:,o] (f32) -> Whbf bf16 row-major;
// el/er via wave reduce.
__global__ __launch_bounds__(64) void wh_el_er_kernel(
    const float* __restrict__ h, const float* __restrict__ W,
    const float* __restrict__ a, ushort* __restrict__ Whbf,
    float* __restrict__ el, float* __restrict__ er) {
  int row = blockIdx.x;           // b*NN + n
  int o = threadIdx.x;
  const float* hr = h + (size_t)row * IN_F;
  float wh = 0.f;
  #pragma unroll 8
  for (int f = 0; f < IN_F; ++f) wh += hr[f] * W[f * OUT_F + o];
  Whbf[(size_t)row * OUT_F + o] = f2bf(wh);
  float vl = wh * a[o];
  float vr = wh * a[OUT_F + o];
  #pragma unroll
  for (int d = 32; d > 0; d >>= 1) {
    vl += __shfl_down(vl, d);
    vr += __shfl_down(vr, d);
  }
  if (o == 0) { el[row] = vl; er[row] = vr; }
}

// Kernel 1b: WhbfT[b][o][j] = Whbf[b][j][o] (bf16 transpose, 64x2048/batch).
__global__ __launch_bounds__(256) void transpose_kernel(
    const ushort* __restrict__ Whbf, ushort* __restrict__ WhbfT) {
  __shared__ uint tile[64][65];
  int b = blockIdx.x >> 5;
  int j0 = (blockIdx.x & 31) << 6;
  int t = threadIdx.x;
  int o = t & 63, jg = t >> 6;
  #pragma unroll
  for (int m = 0; m < 16; ++m) {
    int jj = jg * 16 + m;
    tile[jj][o] = (uint)Whbf[((size_t)(b * NN + j0 + jj)) * OUT_F + o];
  }
  __syncthreads();
  int oo = t >> 2, grp = t & 3;
  uint out[8];
  #pragma unroll
  for (int m = 0; m < 16; m += 2) {
    uint u0 = tile[grp * 16 + m][oo];
    uint u1 = tile[grp * 16 + m + 1][oo];
    out[m >> 1] = u0 | (u1 << 16);
  }
  uint4* dst = (uint4*)(WhbfT + ((size_t)(b * OUT_F + oo)) * NN + j0 + grp * 16);
  dst[0] = *(uint4*)&out[0];
  dst[1] = *(uint4*)&out[4];
}

// Kernel 2: block = 16 rows of one batch, 512 threads (8 waves), 2 rows/wave.
// er staged once in LDS. Phase 1: ALL 16 adj loads (2 rows x 8) issued
// nontemporally into a register array BEFORE consumption (256 B/wave in
// flight -> fills the HBM bandwidth-delay product), then streaming no-max
// masked exp. Attention stores issue BEFORE the pbuf barrier (inv is
// wave-local) so the 128 KB/block drain overlaps barrier + MFMA phase.
// Phase 2: MFMA p @ Wh (wave = o-tile x k-half), cross-khalf LDS reduce,
// scale 1/s, lrelu 0.01.
__global__ __launch_bounds__(512, 4) void attn_kernel(
    const int* __restrict__ adj, const ushort* __restrict__ WhbfT,
    const float* __restrict__ el, const float* __restrict__ er,
    float* __restrict__ attn_out, float* __restrict__ hprime) {
  __shared__ __align__(16) char pbuf[16 * 4096];  // 64 KB: p bf16 [16][2048]
  __shared__ float ers[NN];                       // 8 KB
  __shared__ float red[4][16][17];                // 4.4 KB cross-khalf reduce
  __shared__ float sinv[16];

  int blk = blockIdx.x;
  int b = blk >> 7;             // 128 blocks per batch
  int i0 = (blk & 127) << 4;
  int tid = threadIdx.x;
  int wave = tid >> 6, lane = tid & 63;

  // stage er for this batch into LDS
  ((f32x4*)ers)[tid] = ((const f32x4*)(er + (size_t)b * NN))[tid];
  __syncthreads();

  // ---- Phase 1: preload ALL adj for both rows, then exp ----
  int r0 = wave * 2, r1 = r0 + 1;
  int ia = i0 + r0, ib = i0 + r1;
  float el0 = el[(size_t)b * NN + ia];
  float el1 = el[(size_t)b * NN + ib];
  const i32x4* arow0 = (const i32x4*)(adj + ((size_t)(b * NN + ia)) * NN);
  const i32x4* arow1 = (const i32x4*)(adj + ((size_t)(b * NN + ib)) * NN);

  i32x4 a0[8], a1[8];
  #pragma unroll
  for (int it = 0; it < 8; ++it) {
    a0[it] = __builtin_nontemporal_load(&arow0[lane + 64 * it]);
    a1[it] = __builtin_nontemporal_load(&arow1[lane + 64 * it]);
  }

  uint2 pva0[8], pva1[8];
  float ss0 = 0.f, ss1 = 0.f;
  #pragma unroll
  for (int it = 0; it < 8; ++it) {
    f32x4 ev = *(const f32x4*)&ers[(lane + 64 * it) * 4];
    float evv[4] = {ev.x, ev.y, ev.z, ev.w};
    int   av0[4] = {a0[it].x, a0[it].y, a0[it].z, a0[it].w};
    int   av1[4] = {a1[it].x, a1[it].y, a1[it].z, a1[it].w};
    float pe0[4], pe1[4];
    #pragma unroll
    for (int k = 0; k < 4; ++k) {
      float e0 = el0 + evv[k];
      e0 = fmaxf(e0, 0.2f * e0);            // leaky_relu 0.2
      float x0 = __expf(e0);                // |e| <~ 12, f32-safe unnormalized
      pe0[k] = av0[k] > 0 ? x0 : 0.f;
      ss0 += pe0[k];
      float e1 = el1 + evv[k];
      e1 = fmaxf(e1, 0.2f * e1);
      float x1 = __expf(e1);
      pe1[k] = av1[k] > 0 ? x1 : 0.f;
      ss1 += pe1[k];
    }
    uint2 w0, w1;
    w0.x = (uint)f2bf(pe0[0]) | ((uint)f2bf(pe0[1]) << 16);
    w0.y = (uint)f2bf(pe0[2]) | ((uint)f2bf(pe0[3]) << 16);
    w1.x = (uint)f2bf(pe1[0]) | ((uint)f2bf(pe1[1]) << 16);
    w1.y = (uint)f2bf(pe1[2]) | ((uint)f2bf(pe1[3]) << 16);
    pva0[it] = w0;
    pva1[it] = w1;
  }
  #pragma unroll
  for (int d = 32; d > 0; d >>= 1) {
    ss0 += __shfl_xor(ss0, d);
    ss1 += __shfl_xor(ss1, d);
  }
  float inv0 = 1.f / ss0, inv1 = 1.f / ss1;
  if (lane == 0) { sinv[r0] = inv0; sinv[r1] = inv1; }

  // ---- attention stores FIRST (wave-local inv); drain overlaps barrier,
  //      MFMA phase and epilogue ----
  {
    f32x4* or0 = (f32x4*)(attn_out + ((size_t)(b * NN + ia)) * NN);
    f32x4* or1 = (f32x4*)(attn_out + ((size_t)(b * NN + ib)) * NN);
    #pragma unroll
    for (int it = 0; it < 8; ++it) {
      uint2 w0 = pva0[it], w1 = pva1[it];
      f32x4 v0, v1;
      v0.x = bf2f((ushort)(w0.x & 0xffff)) * inv0;
      v0.y = bf2f((ushort)(w0.x >> 16)) * inv0;
      v0.z = bf2f((ushort)(w0.y & 0xffff)) * inv0;
      v0.w = bf2f((ushort)(w0.y >> 16)) * inv0;
      or0[lane + 64 * it] = v0;
      v1.x = bf2f((ushort)(w1.x & 0xffff)) * inv1;
      v1.y = bf2f((ushort)(w1.x >> 16)) * inv1;
      v1.z = bf2f((ushort)(w1.y & 0xffff)) * inv1;
      v1.w = bf2f((ushort)(w1.y >> 16)) * inv1;
      or1[lane + 64 * it] = v1;
    }
  }

  // ---- p -> swizzled LDS ----
  {
    char* lr0 = pbuf + r0 * 4096;
    char* lr1 = pbuf + r1 * 4096;
    int sw0 = (r0 & 7) << 4, sw1 = (r1 & 7) << 4;
    #pragma unroll
    for (int it = 0; it < 8; ++it) {
      *(uint2*)(lr0 + (((lane + 64 * it) * 8) ^ sw0)) = pva0[it];
      *(uint2*)(lr1 + (((lane + 64 * it) * 8) ^ sw1)) = pva1[it];
    }
  }
  __syncthreads();

  // ---- Phase 2: MFMA p @ Wh; wave = (ntile = w>>1, khalf = w&1) ----
  int ntile = wave >> 1, khalf = wave & 1;
  int o0 = ntile * 16;
  int lo16 = lane & 15, hi4 = lane >> 4;

  const char* prowA = pbuf + lo16 * 4096;
  int swA = (lo16 & 7) << 4;
  const ushort* brow = WhbfT + ((size_t)(b * OUT_F + o0 + lo16)) * NN;

  f32x4 acc = {0.f, 0.f, 0.f, 0.f};
  #pragma unroll 8
  for (int kk = 0; kk < 32; ++kk) {
    int kbase = khalf * 1024 + kk * 32 + hi4 * 8;
    short8 afrag = *(const short8*)(prowA + ((kbase * 2) ^ swA));
    short8 bfrag = *(const short8*)(brow + kbase);
    acc = __builtin_amdgcn_mfma_f32_16x16x32_bf16(afrag, bfrag, acc, 0, 0, 0);
  }

  // ---- cross-khalf reduce + epilogue ----
  if (khalf == 1) {
    #pragma unroll
    for (int q = 0; q < 4; ++q) red[ntile][hi4 * 4 + q][lo16] = acc[q];
  }
  __syncthreads();
  if (khalf == 0) {
    #pragma unroll
    for (int q = 0; q < 4; ++q) {
      int crow = hi4 * 4 + q;
      float v = (acc[q] + red[ntile][crow][lo16]) * sinv[crow];
      v = v > 0.f ? v : 0.01f * v;           // leaky_relu 0.01
      hprime[((size_t)(b * NN + i0 + crow)) * OUT_F + o0 + lo16] = v;
    }
  }
}

extern "C" void kernel_launch(void* const* d_in, const int* in_sizes, int n_in,
                              void* d_out, int out_size, void* d_ws, size_t ws_size,
                              hipStream_t stream) {
  const float* h  = (const float*)d_in[0];
  const int* adj  = (const int*)d_in[1];
  const float* W  = (const float*)d_in[2];
  const float* a  = (const float*)d_in[3];

  float* hprime   = (float*)d_out;                           // B*N*OUT_F
  float* attn_out = (float*)d_out + (size_t)BB * NN * OUT_F; // B*N*N

  // workspace: Whbf bf16 [B*N*64], WhbfT bf16 [B*64*N], el f32, er f32
  ushort* Whbf  = (ushort*)d_ws;
  ushort* WhbfT = Whbf + (size_t)BB * NN * OUT_F;
  float* el = (float*)(WhbfT + (size_t)BB * OUT_F * NN);
  float* er = el + (size_t)BB * NN;

  hipLaunchKernelGGL(wh_el_er_kernel, dim3(BB * NN), dim3(64), 0, stream,
                     h, W, a, Whbf, el, er);
  hipLaunchKernelGGL(transpose_kernel, dim3(BB * (NN / 64)), dim3(256), 0, stream,
                     Whbf, WhbfT);
  hipLaunchKernelGGL(attn_kernel, dim3(BB * (NN / 16)), dim3(512), 0, stream,
                     adj, WhbfT, el, er, attn_out, hprime);
}

// Round 12
// 54.017 us; speedup vs baseline: 1.1877x; 1.0746x over previous
//
#include <hip/hip_runtime.h>

#define NN 2048
#define BB 4
#define IN_F 128
#define OUT_F 64

typedef __attribute__((ext_vector_type(8))) short short8;
typedef __attribute__((ext_vector_type(4))) float f32x4;
typedef __attribute__((ext_vector_type(4))) int i32x4;

__device__ __forceinline__ ushort f2bf(float f) {
  uint u = __float_as_uint(f);
  uint r = (u + 0x7fffu + ((u >> 16) & 1u)) >> 16;   // RNE, finite values
  return (ushort)r;
}
__device__ __forceinline__ float bf2f(ushort s) {
  return __uint_as_float(((uint)s) << 16);
}

// Kernel 1: per row: wh[o] = h[row].W[:,o] (f32) -> Whbf bf16 row-major;
// el/er via wave reduce.
__global__ __launch_bounds__(64) void wh_el_er_kernel(
    const float* __restrict__ h, const float* __restrict__ W,
    const float* __restrict__ a, ushort* __restrict__ Whbf,
    float* __restrict__ el, float* __restrict__ er) {
  int row = blockIdx.x;           // b*NN + n
  int o = threadIdx.x;
  const float* hr = h + (size_t)row * IN_F;
  float wh = 0.f;
  #pragma unroll 8
  for (int f = 0; f < IN_F; ++f) wh += hr[f] * W[f * OUT_F + o];
  Whbf[(size_t)row * OUT_F + o] = f2bf(wh);
  float vl = wh * a[o];
  float vr = wh * a[OUT_F + o];
  #pragma unroll
  for (int d = 32; d > 0; d >>= 1) {
    vl += __shfl_down(vl, d);
    vr += __shfl_down(vr, d);
  }
  if (o == 0) { el[row] = vl; er[row] = vr; }
}

// Kernel 1b: WhbfT[b][o][j] = Whbf[b][j][o] (bf16 transpose, 64x2048/batch).
__global__ __launch_bounds__(256) void transpose_kernel(
    const ushort* __restrict__ Whbf, ushort* __restrict__ WhbfT) {
  __shared__ uint tile[64][65];
  int b = blockIdx.x >> 5;
  int j0 = (blockIdx.x & 31) << 6;
  int t = threadIdx.x;
  int o = t & 63, jg = t >> 6;
  #pragma unroll
  for (int m = 0; m < 16; ++m) {
    int jj = jg * 16 + m;
    tile[jj][o] = (uint)Whbf[((size_t)(b * NN + j0 + jj)) * OUT_F + o];
  }
  __syncthreads();
  int oo = t >> 2, grp = t & 3;
  uint out[8];
  #pragma unroll
  for (int m = 0; m < 16; m += 2) {
    uint u0 = tile[grp * 16 + m][oo];
    uint u1 = tile[grp * 16 + m + 1][oo];
    out[m >> 1] = u0 | (u1 << 16);
  }
  uint4* dst = (uint4*)(WhbfT + ((size_t)(b * OUT_F + oo)) * NN + j0 + grp * 16);
  dst[0] = *(uint4*)&out[0];
  dst[1] = *(uint4*)&out[4];
}

// Kernel 2: block = 16 rows, 512 threads (8 waves). WAVE-SPECIALIZED:
// Phase 1 (all 8 waves): er from LDS; ALL 16 adj loads preloaded NT into
//   regs; streaming no-max masked exp; unnormalized bf16 p -> swizzled pbuf;
//   ONE barrier. No stores issued before the barrier (vmcnt stays clean).
// Phase 2, waves 0-3 (pure MFMA consumers, loads only): full-K p @ Wh for
//   one 16-o tile, two independent acc chains, scale 1/s, lrelu, hprime.
// Phase 2, waves 4-7 (pure store engines): read p from LDS, normalize,
//   32 back-to-back f32x4 attention stores; drain only gates s_endpgm and
//   overlaps the MFMA waves on the same CU.
__global__ __launch_bounds__(512, 4) void attn_kernel(
    const int* __restrict__ adj, const ushort* __restrict__ WhbfT,
    const float* __restrict__ el, const float* __restrict__ er,
    float* __restrict__ attn_out, float* __restrict__ hprime) {
  __shared__ __align__(16) char pbuf[16 * 4096];  // 64 KB: p bf16 [16][2048]
  __shared__ float ers[NN];                       // 8 KB
  __shared__ float sinv[16];

  int blk = blockIdx.x;
  int b = blk >> 7;             // 128 blocks per batch
  int i0 = (blk & 127) << 4;
  int tid = threadIdx.x;
  int wave = tid >> 6, lane = tid & 63;

  // stage er for this batch into LDS
  ((f32x4*)ers)[tid] = ((const f32x4*)(er + (size_t)b * NN))[tid];
  __syncthreads();

  // ---- Phase 1: preload ALL adj for both rows, then exp ----
  int r0 = wave * 2, r1 = r0 + 1;
  int ia = i0 + r0, ib = i0 + r1;
  float el0 = el[(size_t)b * NN + ia];
  float el1 = el[(size_t)b * NN + ib];
  const i32x4* arow0 = (const i32x4*)(adj + ((size_t)(b * NN + ia)) * NN);
  const i32x4* arow1 = (const i32x4*)(adj + ((size_t)(b * NN + ib)) * NN);

  i32x4 a0[8], a1[8];
  #pragma unroll
  for (int it = 0; it < 8; ++it) {
    a0[it] = __builtin_nontemporal_load(&arow0[lane + 64 * it]);
    a1[it] = __builtin_nontemporal_load(&arow1[lane + 64 * it]);
  }

  uint2 pva0[8], pva1[8];
  float ss0 = 0.f, ss1 = 0.f;
  #pragma unroll
  for (int it = 0; it < 8; ++it) {
    f32x4 ev = *(const f32x4*)&ers[(lane + 64 * it) * 4];
    float evv[4] = {ev.x, ev.y, ev.z, ev.w};
    int   av0[4] = {a0[it].x, a0[it].y, a0[it].z, a0[it].w};
    int   av1[4] = {a1[it].x, a1[it].y, a1[it].z, a1[it].w};
    float pe0[4], pe1[4];
    #pragma unroll
    for (int k = 0; k < 4; ++k) {
      float e0 = el0 + evv[k];
      e0 = fmaxf(e0, 0.2f * e0);            // leaky_relu 0.2
      float x0 = __expf(e0);                // |e| <~ 12, f32-safe unnormalized
      pe0[k] = av0[k] > 0 ? x0 : 0.f;
      ss0 += pe0[k];
      float e1 = el1 + evv[k];
      e1 = fmaxf(e1, 0.2f * e1);
      float x1 = __expf(e1);
      pe1[k] = av1[k] > 0 ? x1 : 0.f;
      ss1 += pe1[k];
    }
    uint2 w0, w1;
    w0.x = (uint)f2bf(pe0[0]) | ((uint)f2bf(pe0[1]) << 16);
    w0.y = (uint)f2bf(pe0[2]) | ((uint)f2bf(pe0[3]) << 16);
    w1.x = (uint)f2bf(pe1[0]) | ((uint)f2bf(pe1[1]) << 16);
    w1.y = (uint)f2bf(pe1[2]) | ((uint)f2bf(pe1[3]) << 16);
    pva0[it] = w0;
    pva1[it] = w1;
  }
  #pragma unroll
  for (int d = 32; d > 0; d >>= 1) {
    ss0 += __shfl_xor(ss0, d);
    ss1 += __shfl_xor(ss1, d);
  }
  if (lane == 0) { sinv[r0] = 1.f / ss0; sinv[r1] = 1.f / ss1; }

  // ---- p -> swizzled LDS (no global stores before the barrier) ----
  {
    char* lr0 = pbuf + r0 * 4096;
    char* lr1 = pbuf + r1 * 4096;
    int sw0 = (r0 & 7) << 4, sw1 = (r1 & 7) << 4;
    #pragma unroll
    for (int it = 0; it < 8; ++it) {
      *(uint2*)(lr0 + (((lane + 64 * it) * 8) ^ sw0)) = pva0[it];
      *(uint2*)(lr1 + (((lane + 64 * it) * 8) ^ sw1)) = pva1[it];
    }
  }
  __syncthreads();

  if (wave < 4) {
    // ---- MFMA consumer waves: full K for o-tile `wave`, loads only ----
    int o0 = wave * 16;
    int lo16 = lane & 15, hi4 = lane >> 4;
    const char* prowA = pbuf + lo16 * 4096;
    int swA = (lo16 & 7) << 4;
    const ushort* brow = WhbfT + ((size_t)(b * OUT_F + o0 + lo16)) * NN;

    f32x4 acc0 = {0.f, 0.f, 0.f, 0.f};
    f32x4 acc1 = {0.f, 0.f, 0.f, 0.f};
    #pragma unroll 8
    for (int kk = 0; kk < 32; ++kk) {
      int ka = kk * 32 + hi4 * 8;
      int kb = ka + 1024;
      short8 af0 = *(const short8*)(prowA + ((ka * 2) ^ swA));
      short8 bf0 = *(const short8*)(brow + ka);
      acc0 = __builtin_amdgcn_mfma_f32_16x16x32_bf16(af0, bf0, acc0, 0, 0, 0);
      short8 af1 = *(const short8*)(prowA + ((kb * 2) ^ swA));
      short8 bf1 = *(const short8*)(brow + kb);
      acc1 = __builtin_amdgcn_mfma_f32_16x16x32_bf16(af1, bf1, acc1, 0, 0, 0);
    }
    #pragma unroll
    for (int q = 0; q < 4; ++q) {
      int crow = hi4 * 4 + q;
      float v = (acc0[q] + acc1[q]) * sinv[crow];
      v = v > 0.f ? v : 0.01f * v;           // leaky_relu 0.01
      hprime[((size_t)(b * NN + i0 + crow)) * OUT_F + o0 + lo16] = v;
    }
  } else {
    // ---- store engine waves: normalize + stream attention rows ----
    #pragma unroll
    for (int m = 0; m < 4; ++m) {
      int r = (wave - 4) * 4 + m;
      float inv = sinv[r];
      const char* lr = pbuf + r * 4096;
      int sw = (r & 7) << 4;
      f32x4* orow = (f32x4*)(attn_out + ((size_t)(b * NN + i0 + r)) * NN);
      #pragma unroll
      for (int it = 0; it < 8; ++it) {
        uint2 w2 = *(const uint2*)(lr + (((lane + 64 * it) * 8) ^ sw));
        f32x4 v;
        v.x = bf2f((ushort)(w2.x & 0xffff)) * inv;
        v.y = bf2f((ushort)(w2.x >> 16)) * inv;
        v.z = bf2f((ushort)(w2.y & 0xffff)) * inv;
        v.w = bf2f((ushort)(w2.y >> 16)) * inv;
        orow[lane + 64 * it] = v;
      }
    }
  }
}

extern "C" void kernel_launch(void* const* d_in, const int* in_sizes, int n_in,
                              void* d_out, int out_size, void* d_ws, size_t ws_size,
                              hipStream_t stream) {
  const float* h  = (const float*)d_in[0];
  const int* adj  = (const int*)d_in[1];
  const float* W  = (const float*)d_in[2];
  const float* a  = (const float*)d_in[3];

  float* hprime   = (float*)d_out;                           // B*N*OUT_F
  float* attn_out = (float*)d_out + (size_t)BB * NN * OUT_F; // B*N*N

  // workspace: Whbf bf16 [B*N*64], WhbfT bf16 [B*64*N], el f32, er f32
  ushort* Whbf  = (ushort*)d_ws;
  ushort* WhbfT = Whbf + (size_t)BB * NN * OUT_F;
  float* el = (float*)(WhbfT + (size_t)BB * OUT_F * NN);
  float* er = el + (size_t)BB * NN;

  hipLaunchKernelGGL(wh_el_er_kernel, dim3(BB * NN), dim3(64), 0, stream,
                     h, W, a, Whbf, el, er);
  hipLaunchKernelGGL(transpose_kernel, dim3(BB * (NN / 64)), dim3(256), 0, stream,
                     Whbf, WhbfT);
  hipLaunchKernelGGL(attn_kernel, dim3(BB * (NN / 16)), dim3(512), 0, stream,
                     adj, WhbfT, el, er, attn_out, hprime);
}